// Round 9
// baseline (214.816 us; speedup 1.0000x reference)
//
#include <hip/hip_runtime.h>
#include <hip/hip_bf16.h>

#define B_ 2
#define T_ 4096
#define D_ 2048
#define H_ 4
#define NC 176            // combined proj cols: 128 q | 32 k | 4 w | 12 pad
#define ROWS (B_ * T_)    // 8192
#define TILE_E (16 * NC)  // 2816 elems per 16-row tile of Cb2
#define WTILE_E (16 * D_) // 32768 elems per 16-row n-tile of Wcb2

typedef __attribute__((ext_vector_type(8))) short short8;   // 8 x bf16
typedef __attribute__((ext_vector_type(4))) short short4v;  // 4 x bf16
typedef __attribute__((ext_vector_type(4))) float f32x4;
typedef __attribute__((ext_vector_type(4))) float float4v;

__device__ inline unsigned short f2bf(float f) {
  unsigned u = __float_as_uint(f);
  u += 0x7fffu + ((u >> 16) & 1u);   // RNE
  return (unsigned short)(u >> 16);
}
__device__ inline float bf2f(unsigned short s) {
  return __uint_as_float(((unsigned)s) << 16);
}

// ---------------- Kernel 1: pack weights into octet-tiled bf16 --------------
// Wcb2 layout: E(n, r, k) = n*32768 + (k>>3)*128 + r*8 + (k&7)
__global__ __launch_bounds__(256) void pack_weights(const float* __restrict__ Wq,
                                                    const float* __restrict__ Ww,
                                                    const float* __restrict__ Wk,
                                                    unsigned short* __restrict__ Wcb) {
  int idx = blockIdx.x * 256 + threadIdx.x;
  if (idx >= NC * D_) return;
  int row = idx / D_, col = idx - row * D_;
  float v = 0.f;
  if (row < 128)       v = Wq[row * D_ + col];
  else if (row < 160)  v = Wk[(row - 128) * D_ + col];
  else if (row < 164)  v = Ww[(row - 160) * D_ + col];
  int n = row >> 4, r = row & 15;
  size_t dst = (size_t)n * WTILE_E + (size_t)(col >> 3) * 128 + r * 8 + (col & 7);
  Wcb[dst] = f2bf(v);
}

// ---------------- Kernel 2: Cb2 = bf16(hs) @ Wcb^T (tiled layouts) ----------
// v8: M_rep=2 x split-K=8. 256 blocks x 8 waves (512 thr). Block = 32 rows
// (m-tiles mt0, mt1); wave w owns K-chunk [w*256,(w+1)*256) for BOTH m-tiles,
// reusing each B-fragment for 2 MFMAs -> B L2 traffic 184 MB (was 360) at the
// SAME 2048-wave occupancy. Two-phase 8-way LDS reduce (88 KB).
// DIAGNOSTIC reps param (idempotent) to surface counters in top-5.
__global__ __launch_bounds__(512, 2) void proj_kernel(const float* __restrict__ hs,
                                                      const unsigned short* __restrict__ Wcb,
                                                      unsigned short* __restrict__ Cb,
                                                      int reps) {
  __shared__ f32x4 red[8][11][64];   // 90,112 B -> 1 block/CU (8 waves/CU)

  int wid  = threadIdx.x >> 6;
  int lane = threadIdx.x & 63;
  int lr = lane & 15, lo = lane >> 4;
  int row0 = blockIdx.x * 32;
  int k0   = wid * 256;

  for (int rep = 0; rep < reps; ++rep) {
    int zoff = 0;
    asm volatile("" : "+v"(zoff));   // opaque 0: block cross-rep CSE

    const float* ap0 = hs + (size_t)(row0 + lr) * D_ + k0 + lo * 8 + zoff;
    const float* ap1 = ap0 + (size_t)16 * D_;
    const unsigned short* bbase = Wcb + (size_t)k0 * 16 + lo * 128 + lr * 8 + zoff;

    f32x4 acc0[11], acc1[11];
#pragma unroll
    for (int n = 0; n < 11; ++n) {
      acc0[n] = (f32x4){0.f, 0.f, 0.f, 0.f};
      acc1[n] = (f32x4){0.f, 0.f, 0.f, 0.f};
    }

    float4v Am0[2][2], Am1[2][2];   // [buf][half]
    short8  Bv[2][11];

    Am0[0][0] = *(const float4v*)(ap0);
    Am0[0][1] = *(const float4v*)(ap0 + 4);
    Am1[0][0] = *(const float4v*)(ap1);
    Am1[0][1] = *(const float4v*)(ap1 + 4);
#pragma unroll
    for (int n = 0; n < 11; ++n)
      Bv[0][n] = *(const short8*)(bbase + (size_t)n * WTILE_E);

#pragma unroll
    for (int s = 0; s < 8; ++s) {
      const int cur = s & 1, nxt = cur ^ 1;
      if (s < 7) {   // issue next-step loads BEFORE this step's MFMAs
        Am0[nxt][0] = *(const float4v*)(ap0 + (s + 1) * 32);
        Am0[nxt][1] = *(const float4v*)(ap0 + (s + 1) * 32 + 4);
        Am1[nxt][0] = *(const float4v*)(ap1 + (s + 1) * 32);
        Am1[nxt][1] = *(const float4v*)(ap1 + (s + 1) * 32 + 4);
#pragma unroll
        for (int n = 0; n < 11; ++n)
          Bv[nxt][n] = *(const short8*)(bbase + (size_t)n * WTILE_E + (s + 1) * 512);
      }
      short8 a0, a1;
#pragma unroll
      for (int i = 0; i < 4; ++i) {
        a0[i]     = (short)f2bf(Am0[cur][0][i]);
        a0[i + 4] = (short)f2bf(Am0[cur][1][i]);
        a1[i]     = (short)f2bf(Am1[cur][0][i]);
        a1[i + 4] = (short)f2bf(Am1[cur][1][i]);
      }
#pragma unroll
      for (int n = 0; n < 11; ++n) {
        acc0[n] = __builtin_amdgcn_mfma_f32_16x16x32_bf16(a0, Bv[cur][n], acc0[n], 0, 0, 0);
        acc1[n] = __builtin_amdgcn_mfma_f32_16x16x32_bf16(a1, Bv[cur][n], acc1[n], 0, 0, 0);
      }
    }

    // two-phase 8-way reduce; wave w finalizes n = w and n = w+8 (<11)
#pragma unroll
    for (int ph = 0; ph < 2; ++ph) {
#pragma unroll
      for (int n = 0; n < 11; ++n)
        red[wid][n][lane] = ph == 0 ? acc0[n] : acc1[n];
      __syncthreads();
      unsigned short* cb = Cb + (size_t)((row0 >> 4) + ph) * TILE_E + (lr & 7);
#pragma unroll
      for (int g = 0; g < 2; ++g) {
        int n = wid + g * 8;
        if (n < 11) {
          f32x4 t = red[0][n][lane];
#pragma unroll
          for (int w = 1; w < 8; ++w) {
            f32x4 p = red[w][n][lane];
#pragma unroll
            for (int r = 0; r < 4; ++r) t[r] += p[r];
          }
          int oct = n * 2 + (lr >> 3);
#pragma unroll
          for (int r = 0; r < 4; ++r)
            cb[oct * 128 + (lo * 4 + r) * 8] = f2bf(t[r]);
        }
      }
      __syncthreads();
    }
  }
}

// ---------------- Kernel 3: out[b,t,s] = sum_h w[t,h]*relu(q[t,h,:].k[s,:]) -
// grid (S/128, T/128, B), block 256 (4 waves, 2x2 quadrants of 64x64).
// Epilogue: per-wave LDS transpose -> 256-B row stores. DIAGNOSTIC reps.
__global__ __launch_bounds__(256) void score_kernel(const unsigned short* __restrict__ Cb,
                                                    float* __restrict__ out,
                                                    int reps) {
  __shared__ __align__(16) float tbuf[4][16][72];   // 18,432 B, wave-private

  int b = blockIdx.z, tb = blockIdx.y, sb = blockIdx.x;
  int wid  = threadIdx.x >> 6;
  int lane = threadIdx.x & 63;
  int lr = lane & 15, lo = lane >> 4;
  int wm = wid >> 1, wn = wid & 1;
  int t_base = tb * 128 + wm * 64;
  int s_base = sb * 128 + wn * 64;

  for (int rep = 0; rep < reps; ++rep) {
    int zoff = 0;
    asm volatile("" : "+v"(zoff));   // opaque 0: block cross-rep CSE

    const unsigned short* C2 = Cb + (size_t)b * (T_ / 16) * TILE_E + zoff;
    float* O = out + (size_t)b * T_ * T_ + zoff;

    short8 bf[4];
#pragma unroll
    for (int n = 0; n < 4; ++n)
      bf[n] = *(const short8*)(C2 + (size_t)((s_base >> 4) + n) * TILE_E +
                               (16 + lo) * 128 + lr * 8);

    const f32x4 zero = (f32x4){0.f, 0.f, 0.f, 0.f};
    int rr = lane >> 4;          // epilogue read: row-in-group 0..3
    int cq = (lane & 15) * 4;    // epilogue read: col 0..60 step 4

#pragma unroll
    for (int m = 0; m < 4; ++m) {
      const unsigned short* Ct = C2 + (size_t)((t_base >> 4) + m) * TILE_E;

      short8 af[H_];
#pragma unroll
      for (int h = 0; h < H_; ++h)
        af[h] = *(const short8*)(Ct + (h * 4 + lo) * 128 + lr * 8);

      float wv[4][H_];
      const unsigned short* wp = Ct + 20 * 128 + lo * 32;
#pragma unroll
      for (int r = 0; r < 4; ++r) {
        short4v w4 = *(const short4v*)(wp + r * 8);
#pragma unroll
        for (int h = 0; h < H_; ++h) wv[r][h] = bf2f((unsigned short)w4[h]);
      }

      f32x4 o4[4];
#pragma unroll
      for (int n = 0; n < 4; ++n) {
        f32x4 o = zero;
#pragma unroll
        for (int h = 0; h < H_; ++h) {
          f32x4 c = __builtin_amdgcn_mfma_f32_16x16x32_bf16(af[h], bf[n], zero, 0, 0, 0);
#pragma unroll
          for (int r = 0; r < 4; ++r) o[r] += wv[r][h] * fmaxf(c[r], 0.f);
        }
        o4[n] = o;
      }

#pragma unroll
      for (int n = 0; n < 4; ++n)
#pragma unroll
        for (int r = 0; r < 4; ++r)
          tbuf[wid][lo * 4 + r][n * 16 + lr] = o4[n][r];

      float* Om = O + (size_t)(t_base + m * 16) * T_ + s_base;
#pragma unroll
      for (int j = 0; j < 4; ++j) {
        float4v v = *(const float4v*)&tbuf[wid][rr + 4 * j][cq];
        *(float4v*)(Om + (size_t)(rr + 4 * j) * T_ + cq) = v;
      }
    }
  }
}

// ---------------------------------------------------------------------------
extern "C" void kernel_launch(void* const* d_in, const int* in_sizes, int n_in,
                              void* d_out, int out_size, void* d_ws, size_t ws_size,
                              hipStream_t stream) {
  const float* hs = (const float*)d_in[0];
  const float* Wq = (const float*)d_in[1];
  const float* Ww = (const float*)d_in[2];
  const float* Wk = (const float*)d_in[3];
  float* out = (float*)d_out;

  unsigned short* Wcb = (unsigned short*)d_ws;                      // 720,896 B
  unsigned short* Cb  = (unsigned short*)((char*)d_ws + (1 << 20)); // 2,883,584 B

  pack_weights<<<(NC * D_ + 255) / 256, 256, 0, stream>>>(Wq, Ww, Wk, Wcb);
  proj_kernel<<<ROWS / 32, 512, 0, stream>>>(hs, Wcb, Cb, 6);
  dim3 g(T_ / 128, T_ / 128, B_);
  score_kernel<<<g, 256, 0, stream>>>(Cb, out, 4);
}

// Round 10
// 64.880 us; speedup vs baseline: 3.3110x; 3.3110x over previous
//
#include <hip/hip_runtime.h>
#include <hip/hip_bf16.h>

#define B_ 2
#define T_ 4096
#define D_ 2048
#define H_ 4
#define NC 176            // combined proj cols: 128 q | 32 k | 4 w | 12 pad
#define ROWS (B_ * T_)    // 8192
#define TILE_E (16 * NC)  // 2816 elems per 16-row tile of Cb2
#define WTILE_E (16 * D_) // 32768 elems per 16-row n-tile of Wcb2

typedef __attribute__((ext_vector_type(8))) short short8;   // 8 x bf16
typedef __attribute__((ext_vector_type(4))) short short4v;  // 4 x bf16
typedef __attribute__((ext_vector_type(4))) float f32x4;
typedef __attribute__((ext_vector_type(4))) float float4v;

__device__ inline unsigned short f2bf(float f) {
  unsigned u = __float_as_uint(f);
  u += 0x7fffu + ((u >> 16) & 1u);   // RNE
  return (unsigned short)(u >> 16);
}
__device__ inline float bf2f(unsigned short s) {
  return __uint_as_float(((unsigned)s) << 16);
}

// ---------------- Kernel 1: pack weights into octet-tiled bf16 (vectorized) -
// Wcb2 layout: E(n, r, k) = n*32768 + (k>>3)*128 + r*8 + (k&7)
// One block per combined row; thread = one 8-col octet -> short8 write.
__global__ __launch_bounds__(256) void pack_weights(const float* __restrict__ Wq,
                                                    const float* __restrict__ Ww,
                                                    const float* __restrict__ Wk,
                                                    unsigned short* __restrict__ Wcb) {
  int row = blockIdx.x;          // 0..175
  int cg  = threadIdx.x;         // 0..255 (D_/8 octets)
  int col = cg * 8;

  const float* src = nullptr;
  if (row < 128)       src = Wq + (size_t)row * D_;
  else if (row < 160)  src = Wk + (size_t)(row - 128) * D_;
  else if (row < 164)  src = Ww + (size_t)(row - 160) * D_;

  short8 v;
  if (src) {
    float4v f0 = *(const float4v*)(src + col);
    float4v f1 = *(const float4v*)(src + col + 4);
#pragma unroll
    for (int i = 0; i < 4; ++i) {
      v[i]     = (short)f2bf(f0[i]);
      v[i + 4] = (short)f2bf(f1[i]);
    }
  } else {
#pragma unroll
    for (int i = 0; i < 8; ++i) v[i] = 0;
  }
  int n = row >> 4, r = row & 15;
  *(short8*)&Wcb[(size_t)n * WTILE_E + (size_t)cg * 128 + r * 8] = v;
}

// ---------------- Kernel 2: Cb2 = bf16(hs) @ Wcb^T (tiled layouts) ----------
// v9: 512 blocks x 8 waves (512 thr). Block = ONE 16-row m-tile; wave w owns
// K-chunk [w*256,(w+1)*256) (8 steps of K=32). 4096 waves -> 16 waves/CU,
// 2 blocks/CU (LDS 49KB). Register double-buffer; 8-way LDS reduce in two
// n-rounds (n 0-5, 6-10) to keep LDS under 64KB.
__global__ __launch_bounds__(512) void proj_kernel(const float* __restrict__ hs,
                                                   const unsigned short* __restrict__ Wcb,
                                                   unsigned short* __restrict__ Cb) {
  __shared__ f32x4 red[8][6][64];   // 49,152 B -> 2 blocks/CU

  int wid  = threadIdx.x >> 6;
  int lane = threadIdx.x & 63;
  int lr = lane & 15, lo = lane >> 4;
  int row0 = blockIdx.x * 16;
  int k0   = wid * 256;

  const float*          ap    = hs  + (size_t)(row0 + lr) * D_ + k0 + lo * 8;
  const unsigned short* bbase = Wcb + (size_t)k0 * 16 + lo * 128 + lr * 8;

  f32x4 acc[11];
#pragma unroll
  for (int n = 0; n < 11; ++n) acc[n] = (f32x4){0.f, 0.f, 0.f, 0.f};

  float4v A0[2], A1[2];
  short8  Bv[2][11];

  // prologue: load step 0
  A0[0] = *(const float4v*)(ap);
  A1[0] = *(const float4v*)(ap + 4);
#pragma unroll
  for (int n = 0; n < 11; ++n)
    Bv[0][n] = *(const short8*)(bbase + (size_t)n * WTILE_E);

#pragma unroll
  for (int s = 0; s < 8; ++s) {
    const int cur = s & 1, nxt = cur ^ 1;
    if (s < 7) {   // issue next-step loads BEFORE this step's MFMAs
      A0[nxt] = *(const float4v*)(ap + (s + 1) * 32);
      A1[nxt] = *(const float4v*)(ap + (s + 1) * 32 + 4);
#pragma unroll
      for (int n = 0; n < 11; ++n)
        Bv[nxt][n] = *(const short8*)(bbase + (size_t)n * WTILE_E + (s + 1) * 512);
    }
    short8 a;
#pragma unroll
    for (int i = 0; i < 4; ++i) {
      a[i]     = (short)f2bf(A0[cur][i]);
      a[i + 4] = (short)f2bf(A1[cur][i]);
    }
#pragma unroll
    for (int n = 0; n < 11; ++n)
      acc[n] = __builtin_amdgcn_mfma_f32_16x16x32_bf16(a, Bv[cur][n], acc[n], 0, 0, 0);
  }

  // 8-way reduce in two n-rounds; wave w finalizes n = ns + w.
  unsigned short* cb = Cb + (size_t)(row0 >> 4) * TILE_E + (lr & 7);
#pragma unroll
  for (int g = 0; g < 2; ++g) {
    const int ns = g * 6;
    const int cnt = (g == 0) ? 6 : 5;
#pragma unroll
    for (int j = 0; j < 6; ++j)
      if (j < cnt) red[wid][j][lane] = acc[ns + j];
    __syncthreads();
    if (wid < cnt) {
      int n = ns + wid;
      f32x4 t = red[0][wid][lane];
#pragma unroll
      for (int w = 1; w < 8; ++w) {
        f32x4 p = red[w][wid][lane];
#pragma unroll
        for (int r = 0; r < 4; ++r) t[r] += p[r];
      }
      int oct = n * 2 + (lr >> 3);
#pragma unroll
      for (int r = 0; r < 4; ++r)
        cb[oct * 128 + (lo * 4 + r) * 8] = f2bf(t[r]);
    }
    __syncthreads();
  }
}

// ---------------- Kernel 3: out[b,t,s] = sum_h w[t,h]*relu(q[t,h,:].k[s,:]) -
// grid (S/128, T/128, B), block 256 (4 waves, 2x2 quadrants of 64x64).
// tbuf stride 76: lo-group offset 16 mod 32 banks -> free 2-way (was 4-way).
// Non-temporal dwordx4 stores: output is never re-read, don't thrash L2.
__global__ __launch_bounds__(256) void score_kernel(const unsigned short* __restrict__ Cb,
                                                    float* __restrict__ out) {
  __shared__ __align__(16) float tbuf[4][16][76];   // 19,456 B, wave-private

  int b = blockIdx.z, tb = blockIdx.y, sb = blockIdx.x;
  int wid  = threadIdx.x >> 6;
  int lane = threadIdx.x & 63;
  int lr = lane & 15, lo = lane >> 4;
  int wm = wid >> 1, wn = wid & 1;
  int t_base = tb * 128 + wm * 64;
  int s_base = sb * 128 + wn * 64;

  const unsigned short* C2 = Cb + (size_t)b * (T_ / 16) * TILE_E;
  float* O = out + (size_t)b * T_ * T_;

  // B-frags (k part, cols 128..159 -> octet 16+lo): shared across heads
  short8 bf[4];
#pragma unroll
  for (int n = 0; n < 4; ++n)
    bf[n] = *(const short8*)(C2 + (size_t)((s_base >> 4) + n) * TILE_E +
                             (16 + lo) * 128 + lr * 8);

  const f32x4 zero = (f32x4){0.f, 0.f, 0.f, 0.f};
  int rr = lane >> 4;          // epilogue read: row-in-group 0..3
  int cq = (lane & 15) * 4;    // epilogue read: col 0..60 step 4

#pragma unroll
  for (int m = 0; m < 4; ++m) {
    const unsigned short* Ct = C2 + (size_t)((t_base >> 4) + m) * TILE_E;

    short8 af[H_];
#pragma unroll
    for (int h = 0; h < H_; ++h)
      af[h] = *(const short8*)(Ct + (h * 4 + lo) * 128 + lr * 8);

    float wv[4][H_];
    const unsigned short* wp = Ct + 20 * 128 + lo * 32;
#pragma unroll
    for (int r = 0; r < 4; ++r) {
      short4v w4 = *(const short4v*)(wp + r * 8);
#pragma unroll
      for (int h = 0; h < H_; ++h) wv[r][h] = bf2f((unsigned short)w4[h]);
    }

    f32x4 o4[4];
#pragma unroll
    for (int n = 0; n < 4; ++n) {
      f32x4 o = zero;
#pragma unroll
      for (int h = 0; h < H_; ++h) {
        f32x4 c = __builtin_amdgcn_mfma_f32_16x16x32_bf16(af[h], bf[n], zero, 0, 0, 0);
#pragma unroll
        for (int r = 0; r < 4; ++r) o[r] += wv[r][h] * fmaxf(c[r], 0.f);
      }
      o4[n] = o;
    }

    // transpose via wave-private LDS: write C/D-layout, read row-contiguous
#pragma unroll
    for (int n = 0; n < 4; ++n)
#pragma unroll
      for (int r = 0; r < 4; ++r)
        tbuf[wid][lo * 4 + r][n * 16 + lr] = o4[n][r];

    float* Om = O + (size_t)(t_base + m * 16) * T_ + s_base;
#pragma unroll
    for (int j = 0; j < 4; ++j) {
      float4v v = *(const float4v*)&tbuf[wid][rr + 4 * j][cq];
      __builtin_nontemporal_store(v, (float4v*)(Om + (size_t)(rr + 4 * j) * T_ + cq));
    }
  }
}

// ---------------------------------------------------------------------------
extern "C" void kernel_launch(void* const* d_in, const int* in_sizes, int n_in,
                              void* d_out, int out_size, void* d_ws, size_t ws_size,
                              hipStream_t stream) {
  const float* hs = (const float*)d_in[0];
  const float* Wq = (const float*)d_in[1];
  const float* Ww = (const float*)d_in[2];
  const float* Wk = (const float*)d_in[3];
  float* out = (float*)d_out;

  unsigned short* Wcb = (unsigned short*)d_ws;                      // 720,896 B
  unsigned short* Cb  = (unsigned short*)((char*)d_ws + (1 << 20)); // 2,883,584 B

  pack_weights<<<NC, 256, 0, stream>>>(Wq, Ww, Wk, Wcb);
  proj_kernel<<<ROWS / 16, 512, 0, stream>>>(hs, Wcb, Cb);
  dim3 g(T_ / 128, T_ / 128, B_);
  score_kernel<<<g, 256, 0, stream>>>(Cb, out);
}